// Round 9
// baseline (156.428 us; speedup 1.0000x reference)
//
#include <hip/hip_runtime.h>
#include <hip/hip_bf16.h>

// n=16,c=256,h=w=64 -> 4096 independent 64x64 tiles.
// A = softmax_h(X^T); Xn = rowwise LN(X) (unbiased std, eps on std);
// node = A@Xn; out = relu(node@W).
// MFMA 32x32x16_bf16. A = hi only; Xn, W, node = hi/lo bf16 pairs.
// R8: 4 tiles per block, software-pipelined: X loads for tile t+1 issued
// before the mm phases of tile t; raw s_barrier (lgkm drain only, NO vmcnt
// drain) keeps the prefetch in flight across barriers. LDS dbuf 48KB.

typedef __attribute__((ext_vector_type(8)))  short  s16x8;   // MFMA A/B frag
typedef __attribute__((ext_vector_type(16))) float  f32x16;  // MFMA C/D frag
typedef __attribute__((ext_vector_type(8)))  unsigned short us8;

__device__ __forceinline__ unsigned short f2bf(float x) {
    __hip_bfloat16 b = __float2bfloat16(x);
    return __builtin_bit_cast(unsigned short, b);
}
__device__ __forceinline__ float bf2f(unsigned short h) {
    unsigned u = ((unsigned)h) << 16;
    return __builtin_bit_cast(float, u);
}
// swizzle: balances b128 MFMA reads AND strided b16 LN/node writes
__device__ __forceinline__ int swz(int row) {
    return ((row & 7) ^ ((row >> 3) & 7)) << 3;
}
__device__ __forceinline__ int swidx(int row, int k) {
    return row * 64 + (k ^ swz(row));
}

// compiler fence + raw barrier (does NOT drain vmcnt -> prefetch stays in flight)
#define LGKM_DRAIN()  asm volatile("s_waitcnt lgkmcnt(0)" ::: "memory")
#define RAW_BAR()     do { asm volatile("" ::: "memory");                 \
                           __builtin_amdgcn_s_barrier();                  \
                           asm volatile("" ::: "memory"); } while (0)

// one-time W -> WT[j][k] bf16 hi/lo into ws, LINEAR layout (register frags)
__global__ void prep_w(const float* __restrict__ Wg, unsigned short* __restrict__ ws) {
    const int gid = blockIdx.x * 256 + threadIdx.x;  // 0..4095
    const int j = gid & 63;          // col of W
    const int k = gid >> 6;          // row of W
    const float x = Wg[k * 64 + j];  // coalesced over j
    const unsigned short hh = f2bf(x);
    ws[j * 64 + k] = hh;             // WT[j][k]
    ws[4096 + j * 64 + k] = f2bf(x - bf2f(hh));
}

__global__ __launch_bounds__(256, 3)
void gnn_mfma(const float* __restrict__ X, const unsigned short* __restrict__ Wp,
              const float* __restrict__ a2, const float* __restrict__ b2,
              float* __restrict__ out)
{
    // 6 x 8KB = 48KB -> 3 blocks/CU
    __shared__ __align__(16) unsigned short bufA [2][64 * 64]; // A hi; later node hi
    __shared__ __align__(16) unsigned short bufXh[2][64 * 64]; // XnT hi
    __shared__ __align__(16) unsigned short bufXl[2][64 * 64]; // XnT lo; later node lo

    const int tid = threadIdx.x;
    const int b   = blockIdx.x;             // 0..1023, owns tiles 4b..4b+3

    const int wid  = tid >> 6;
    const int lane = tid & 63;
    const int r    = lane & 31;
    const int hl   = lane >> 5;
    const int R = (wid & 1) * 32;           // output row base (w1)
    const int C = (wid >> 1) * 32;          // output col base (w2 / j)
    const int rowA = R + r;                 // A / node row
    const int rowB = C + r;                 // XnT row / WT row (j)
    const int swA = swz(rowA);
    const int swB = swz(rowB);

    // softmax mapping
    const int wi = tid >> 2;                // 0..63 (X column)
    const int h0 = (tid & 3) << 4;          // 0,16,32,48
    // LN mapping
    const int h_  = tid >> 2;               // 0..63 (X row)
    const int c0_ = (tid & 3) << 4;

    // ---- W fragments: persistent registers (L2-resident source) ----
    us8 wh0, wh1, wh2, wh3, wl0, wl1, wl2, wl3;
    {
        const us8* ph = (const us8*)&Wp[rowB * 64 + 8 * hl];
        const us8* pl = (const us8*)&Wp[4096 + rowB * 64 + 8 * hl];
        wh0 = ph[0]; wh1 = ph[2]; wh2 = ph[4]; wh3 = ph[6];
        wl0 = pl[0]; wl1 = pl[2]; wl2 = pl[4]; wl3 = pl[6];
    }
    // ---- a2/b2: persistent registers ----
    float av[16], bv[16];
    #pragma unroll
    for (int i = 0; i < 4; ++i) {
        float4 ta = *(const float4*)&a2[c0_ + 4 * i];
        float4 tb = *(const float4*)&b2[c0_ + 4 * i];
        av[4*i] = ta.x; av[4*i+1] = ta.y; av[4*i+2] = ta.z; av[4*i+3] = ta.w;
        bv[4*i] = tb.x; bv[4*i+1] = tb.y; bv[4*i+2] = tb.z; bv[4*i+3] = tb.w;
    }

    // ---- prefetch registers ----
    float  sm[16];      // softmax column gather
    float4 ln4[4];      // LN row

    const float* xb = X + (size_t)(4 * b) * 4096;
    #pragma unroll
    for (int i = 0; i < 16; ++i) sm[i] = xb[(h0 + i) * 64 + wi];
    #pragma unroll
    for (int i = 0; i < 4; ++i) ln4[i] = *(const float4*)&xb[h_ * 64 + c0_ + 4 * i];

    #pragma unroll
    for (int t = 0; t < 4; ++t) {
        const int cur = t & 1;

        // ---- softmax (consumes sm) -> bufA[cur] ----
        {
            float m = sm[0];
            #pragma unroll
            for (int i = 1; i < 16; ++i) m = fmaxf(m, sm[i]);
            m = fmaxf(m, __shfl_xor(m, 1));
            m = fmaxf(m, __shfl_xor(m, 2));
            float s = 0.f;
            float e[16];
            #pragma unroll
            for (int i = 0; i < 16; ++i) { e[i] = __expf(sm[i] - m); s += e[i]; }
            s += __shfl_xor(s, 1);
            s += __shfl_xor(s, 2);
            const float inv = 1.0f / s;
            us8 hv0, hv1;
            #pragma unroll
            for (int i = 0; i < 8; ++i) hv0[i] = f2bf(e[i] * inv);
            #pragma unroll
            for (int i = 0; i < 8; ++i) hv1[i] = f2bf(e[8 + i] * inv);
            const int sw = swz(wi);
            *(us8*)&bufA[cur][wi * 64 + (h0 ^ sw)]       = hv0;
            *(us8*)&bufA[cur][wi * 64 + ((h0 + 8) ^ sw)] = hv1;
        }
        // ---- layernorm (consumes ln4) -> bufXh/bufXl[cur] ----
        {
            float x[16];
            #pragma unroll
            for (int i = 0; i < 4; ++i) {
                x[4*i] = ln4[i].x; x[4*i+1] = ln4[i].y;
                x[4*i+2] = ln4[i].z; x[4*i+3] = ln4[i].w;
            }
            float s = 0.f, sq = 0.f;
            #pragma unroll
            for (int i = 0; i < 16; ++i) { s += x[i]; sq += x[i] * x[i]; }
            s  += __shfl_xor(s, 1);  s  += __shfl_xor(s, 2);
            sq += __shfl_xor(sq, 1); sq += __shfl_xor(sq, 2);
            const float mean = s * (1.0f / 64.0f);
            float var = (sq - 64.0f * mean * mean) * (1.0f / 63.0f);
            var = fmaxf(var, 0.0f);
            const float invstd = 1.0f / (sqrtf(var) + 1e-6f);
            #pragma unroll
            for (int i = 0; i < 16; ++i) {
                const float xn = av[i] * (x[i] - mean) * invstd + bv[i];
                const unsigned short hh = f2bf(xn);
                const int idx = swidx(c0_ + i, h_);
                bufXh[cur][idx] = hh;
                bufXl[cur][idx] = f2bf(xn - bf2f(hh));
            }
        }

        // ---- issue prefetch for tile t+1 (in flight through mm phases) ----
        if (t < 3) {
            const float* xn_ = X + (size_t)(4 * b + t + 1) * 4096;
            #pragma unroll
            for (int i = 0; i < 16; ++i) sm[i] = xn_[(h0 + i) * 64 + wi];
            #pragma unroll
            for (int i = 0; i < 4; ++i) ln4[i] = *(const float4*)&xn_[h_ * 64 + c0_ + 4 * i];
        }

        LGKM_DRAIN();          // seg1 LDS writes visible
        RAW_BAR();             // (no vmcnt drain: prefetch stays in flight)

        // ---- mm1: node = A @ Xn, 8 MFMAs ----
        f32x16 acc;
        #pragma unroll
        for (int i = 0; i < 16; ++i) acc[i] = 0.f;
        #pragma unroll
        for (int t4 = 0; t4 < 4; ++t4) {
            const int k0 = 16 * t4 + 8 * hl;
            s16x8 aH = *(const s16x8*)&bufA [cur][rowA * 64 + (k0 ^ swA)];
            s16x8 bH = *(const s16x8*)&bufXh[cur][rowB * 64 + (k0 ^ swB)];
            s16x8 bL = *(const s16x8*)&bufXl[cur][rowB * 64 + (k0 ^ swB)];
            acc = __builtin_amdgcn_mfma_f32_32x32x16_bf16(aH, bH, acc, 0, 0, 0);
            acc = __builtin_amdgcn_mfma_f32_32x32x16_bf16(aH, bL, acc, 0, 0, 0);
        }
        RAW_BAR();             // all mm1 reads consumed before node overwrite

        // ---- node[w1][w2]: hi -> bufA[cur], lo -> bufXl[cur] ----
        #pragma unroll
        for (int g = 0; g < 16; ++g) {
            const int w1 = R + (g & 3) + 8 * (g >> 2) + 4 * hl;  // C/D row map
            const int idx = swidx(w1, C + r);
            const float xv = acc[g];
            const unsigned short hh = f2bf(xv);
            bufA [cur][idx] = hh;
            bufXl[cur][idx] = f2bf(xv - bf2f(hh));
        }
        LGKM_DRAIN();
        RAW_BAR();

        // ---- mm2: out = relu(node @ W), 12 MFMAs, W in regs ----
        f32x16 acc2;
        #pragma unroll
        for (int i = 0; i < 16; ++i) acc2[i] = 0.f;
        #pragma unroll
        for (int t4 = 0; t4 < 4; ++t4) {
            const int k0 = 16 * t4 + 8 * hl;
            s16x8 nH = *(const s16x8*)&bufA [cur][rowA * 64 + (k0 ^ swA)];
            s16x8 nL = *(const s16x8*)&bufXl[cur][rowA * 64 + (k0 ^ swA)];
            const s16x8 wH = __builtin_bit_cast(s16x8, t4 == 0 ? wh0 : t4 == 1 ? wh1 : t4 == 2 ? wh2 : wh3);
            const s16x8 wL = __builtin_bit_cast(s16x8, t4 == 0 ? wl0 : t4 == 1 ? wl1 : t4 == 2 ? wl2 : wl3);
            acc2 = __builtin_amdgcn_mfma_f32_32x32x16_bf16(nH, wH, acc2, 0, 0, 0);
            acc2 = __builtin_amdgcn_mfma_f32_32x32x16_bf16(nH, wL, acc2, 0, 0, 0);
            acc2 = __builtin_amdgcn_mfma_f32_32x32x16_bf16(nL, wH, acc2, 0, 0, 0);
        }

        float* ob = out + (size_t)(4 * b + t) * 4096;
        #pragma unroll
        for (int g = 0; g < 16; ++g) {
            const int w1 = R + (g & 3) + 8 * (g >> 2) + 4 * hl;
            ob[w1 * 64 + C + r] = fmaxf(acc2[g], 0.f);
        }
    }
}

extern "C" void kernel_launch(void* const* d_in, const int* in_sizes, int n_in,
                              void* d_out, int out_size, void* d_ws, size_t ws_size,
                              hipStream_t stream) {
    const float* X  = (const float*)d_in[0];
    const float* W  = (const float*)d_in[1];
    const float* a2 = (const float*)d_in[2];
    const float* b2 = (const float*)d_in[3];
    float* out = (float*)d_out;
    unsigned short* wp = (unsigned short*)d_ws;   // 16KB: WT hi[4096] + lo[4096]
    prep_w<<<16, 256, 0, stream>>>(W, wp);
    gnn_mfma<<<1024, 256, 0, stream>>>(X, wp, a2, b2, out);
}